// Round 1
// baseline (132.156 us; speedup 1.0000x reference)
//
#include <hip/hip_runtime.h>

// Problem constants (fixed by reference setup_inputs)
#define BN 512
#define CCH 32
#define TT 4096

__global__ void adaptive_pool_kernel(const float* __restrict__ f,
                                     const float* __restrict__ m,
                                     const int* __restrict__ vlen,
                                     float* __restrict__ out_f,
                                     float* __restrict__ out_m,
                                     int K, int total) {
    int tid = blockIdx.x * blockDim.x + threadIdx.x;
    if (tid >= total) return;

    int k  = tid % K;
    int bc = tid / K;          // b*CCH + c
    int b  = bc / CCH;

    // valid_lengths may be int64 (JAX x64 on) or int32 (x64 off).
    // If int64 little-endian: all high words (odd int32 indices) are 0
    // since values are in [0, 4096). Probability of false positive with
    // int32 data: (1/4096)^8 ~ 0.
    bool is64 = ((vlen[1] | vlen[3] | vlen[5] | vlen[7] |
                  vlen[9] | vlen[11] | vlen[13] | vlen[15]) == 0);
    int len = is64 ? vlen[2 * b] : vlen[b];

    int L = len < 1 ? 1 : (len > TT ? TT : len);
    int off = TT - L;

    unsigned uk = (unsigned)k, uK = (unsigned)K, uL = (unsigned)L;
    unsigned s_rel = (uL * uk) / uK;
    unsigned e_rel = (uL * (uk + 1u) + uK - 1u) / uK;

    int si = (int)s_rel + off;
    int ei = (int)e_rel + off;
    if (ei > TT) ei = TT;
    if (si < 0) si = 0;
    int count = ei - si;
    if (count < 1) count = 1;

    long long base = (long long)bc * TT;
    float sf = 0.0f, sm = 0.0f;
    for (int t = si; t < ei; ++t) {
        sf += f[base + t];
        sm += m[base + t];
    }
    float inv = 1.0f / (float)count;
    out_f[tid] = sf * inv;
    out_m[tid] = sm * inv;
}

extern "C" void kernel_launch(void* const* d_in, const int* in_sizes, int n_in,
                              void* d_out, int out_size, void* d_ws, size_t ws_size,
                              hipStream_t stream) {
    const float* f    = (const float*)d_in[0];
    const float* m    = (const float*)d_in[1];
    const int*   vlen = (const int*)d_in[2];

    // K derived from output size: out = 2 * BN * C * K floats
    int K = out_size / (2 * BN * CCH);
    if (K < 1) K = 1;

    float* out_f = (float*)d_out;
    float* out_m = out_f + (size_t)BN * CCH * K;

    int total = BN * CCH * K;
    int block = 256;
    int grid  = (total + block - 1) / block;
    adaptive_pool_kernel<<<grid, block, 0, stream>>>(f, m, vlen, out_f, out_m, K, total);
}

// Round 2
// 61.595 us; speedup vs baseline: 2.1456x; 2.1456x over previous
//
#include <hip/hip_runtime.h>

// Problem constants (fixed by reference setup_inputs)
#define BN 512
#define CCH 32
#define TT 4096

// Pad LDS by +4 floats per 32: keeps float4 (16B) alignment for staging
// writes (4-aligned indices stay 4-aligned) while breaking power-of-2
// strides for the per-bin reads (stride ~L/K floats between lanes).
__device__ __forceinline__ int padidx(int i) { return i + ((i >> 5) << 2); }

__global__ __launch_bounds__(256) void adaptive_pool_lds(
    const float* __restrict__ f, const float* __restrict__ m,
    const int* __restrict__ vlen,
    float* __restrict__ out_f, float* __restrict__ out_m, int K)
{
    __shared__ float sf[4608];   // padidx(4095) = 4095+508 < 4608
    __shared__ float sm[4608];

    int bc = blockIdx.x;         // b*CCH + c
    int b  = bc / CCH;

    // valid_lengths may be int64 (JAX x64 on) or int32 (x64 off).
    // int64 little-endian: all high words (odd int32 indices) are 0 since
    // values are in [0, 4096).
    bool is64 = ((vlen[1] | vlen[3] | vlen[5] | vlen[7] |
                  vlen[9] | vlen[11] | vlen[13] | vlen[15]) == 0);
    int len = is64 ? vlen[2 * b] : vlen[b];

    int L = len < 1 ? 1 : (len > TT ? TT : len);
    int off = TT - L;
    int a0 = off & ~3;           // 16B-aligned start of staged region

    const float* fr = f + (size_t)bc * TT;
    const float* mr = m + (size_t)bc * TT;

    // Stage window [a0, TT) of both rows into LDS, coalesced float4.
    int nv = (TT - a0) >> 2;     // number of float4s
    for (int idx = threadIdx.x; idx < nv; idx += 256) {
        int t0 = a0 + (idx << 2);
        float4 vf = *(const float4*)(fr + t0);
        float4 vm = *(const float4*)(mr + t0);
        int p = padidx(t0);      // multiple of 4 -> 16B-aligned LDS addr
        *(float4*)(&sf[p]) = vf;
        *(float4*)(&sm[p]) = vm;
    }
    __syncthreads();

    // Each thread computes bin k for both outputs.
    for (int k = threadIdx.x; k < K; k += 256) {
        unsigned uL = (unsigned)L, uK = (unsigned)K, uk = (unsigned)k;
        int si = off + (int)((uL * uk) / uK);
        int ei = off + (int)((uL * (uk + 1u) + uK - 1u) / uK);
        if (ei > TT) ei = TT;
        int count = ei - si;
        if (count < 1) count = 1;

        float af = 0.0f, am = 0.0f;
        for (int t = si; t < ei; ++t) {
            int p = padidx(t);
            af += sf[p];
            am += sm[p];
        }
        float inv = 1.0f / (float)count;
        size_t o = (size_t)bc * K + k;
        out_f[o] = af * inv;
        out_m[o] = am * inv;
    }
}

extern "C" void kernel_launch(void* const* d_in, const int* in_sizes, int n_in,
                              void* d_out, int out_size, void* d_ws, size_t ws_size,
                              hipStream_t stream) {
    const float* f    = (const float*)d_in[0];
    const float* m    = (const float*)d_in[1];
    const int*   vlen = (const int*)d_in[2];

    // K derived from output size: out = 2 * BN * C * K floats
    int K = out_size / (2 * BN * CCH);
    if (K < 1) K = 1;

    float* out_f = (float*)d_out;
    float* out_m = out_f + (size_t)BN * CCH * K;

    int grid = BN * CCH;
    adaptive_pool_lds<<<grid, 256, 0, stream>>>(f, m, vlen, out_f, out_m, K);
}

// Round 3
// 55.705 us; speedup vs baseline: 2.3724x; 1.1057x over previous
//
#include <hip/hip_runtime.h>

// Problem constants (fixed by reference setup_inputs)
#define BN 512
#define CCH 32
#define TT 4096
#define RPB 8   // rows per block; grid = BN*CCH/RPB = 2048

// Pad LDS by +4 floats per 32: keeps float4 (16B) alignment for staging
// writes while spreading the ~stride-8 bin reads across banks.
__device__ __forceinline__ int padidx(int i) { return i + ((i >> 5) << 2); }

__global__ __launch_bounds__(256) void pool_pipe(
    const float* __restrict__ f, const float* __restrict__ m,
    const int* __restrict__ vlen,
    float* __restrict__ out_f, float* __restrict__ out_m, int K)
{
    __shared__ float sf[4608];   // padidx(4095) = 4603 < 4608
    __shared__ float sm[4608];

    const int tid = threadIdx.x;
    const int nb  = gridDim.x;

    // valid_lengths may be int64 (JAX x64 on) or int32 (x64 off).
    // int64 LE: all high words are 0 since values < 4096.
    bool is64 = ((vlen[1] | vlen[3] | vlen[5] | vlen[7] |
                  vlen[9] | vlen[11] | vlen[13] | vlen[15]) == 0);

    // Named float4 prefetch registers (static indices -> stay in VGPRs).
    float4 rf0, rf1, rf2, rf3, rm0, rm1, rm2, rm3;
    int bc, L, off, a0, nv;

    // --- row-parameter computation ---
    #define ROW_PARAMS(j)                                              \
        do {                                                           \
            bc = blockIdx.x + (j) * nb;                                \
            int b_ = bc / CCH;                                         \
            int len_ = is64 ? vlen[2 * b_] : vlen[b_];                 \
            L = len_ < 1 ? 1 : (len_ > TT ? TT : len_);                \
            off = TT - L;                                              \
            a0 = off & ~3;                                             \
            nv = (TT - a0) >> 2;                                       \
        } while (0)

    // --- issue global loads for row described by (bc, a0, nv) ---
    #define ISSUE_LOADS()                                              \
        do {                                                           \
            const float* fr_ = f + (size_t)bc * TT + a0;               \
            const float* mr_ = m + (size_t)bc * TT + a0;               \
            int i0_ = tid, i1_ = tid + 256, i2_ = tid + 512, i3_ = tid + 768; \
            if (i0_ < nv) { rf0 = *(const float4*)(fr_ + 4 * i0_);     \
                            rm0 = *(const float4*)(mr_ + 4 * i0_); }   \
            if (i1_ < nv) { rf1 = *(const float4*)(fr_ + 4 * i1_);     \
                            rm1 = *(const float4*)(mr_ + 4 * i1_); }   \
            if (i2_ < nv) { rf2 = *(const float4*)(fr_ + 4 * i2_);     \
                            rm2 = *(const float4*)(mr_ + 4 * i2_); }   \
            if (i3_ < nv) { rf3 = *(const float4*)(fr_ + 4 * i3_);     \
                            rm3 = *(const float4*)(mr_ + 4 * i3_); }   \
        } while (0)

    // Prologue: prefetch row 0.
    ROW_PARAMS(0);
    ISSUE_LOADS();

    for (int j = 0; j < RPB; ++j) {
        // Write the prefetched row into LDS (guards use this row's nv/a0).
        {
            int i0_ = tid, i1_ = tid + 256, i2_ = tid + 512, i3_ = tid + 768;
            if (i0_ < nv) { int p = padidx(a0 + 4 * i0_);
                            *(float4*)&sf[p] = rf0; *(float4*)&sm[p] = rm0; }
            if (i1_ < nv) { int p = padidx(a0 + 4 * i1_);
                            *(float4*)&sf[p] = rf1; *(float4*)&sm[p] = rm1; }
            if (i2_ < nv) { int p = padidx(a0 + 4 * i2_);
                            *(float4*)&sf[p] = rf2; *(float4*)&sm[p] = rm2; }
            if (i3_ < nv) { int p = padidx(a0 + 4 * i3_);
                            *(float4*)&sf[p] = rf3; *(float4*)&sm[p] = rm3; }
        }
        __syncthreads();

        // Save current row's compute parameters.
        int cbc = bc, cL = L, coff = off;

        // Issue next row's global loads NOW — they fly during bin-compute.
        if (j + 1 < RPB) {
            ROW_PARAMS(j + 1);
            ISSUE_LOADS();
        }

        // Compute bins of the current row from LDS.
        for (int k = tid; k < K; k += 256) {
            unsigned uL = (unsigned)cL, uK = (unsigned)K, uk = (unsigned)k;
            int si = coff + (int)((uL * uk) / uK);
            int ei = coff + (int)((uL * (uk + 1u) + uK - 1u) / uK);
            if (ei > TT) ei = TT;
            int count = ei - si;
            if (count < 1) count = 1;

            float af = 0.0f, am = 0.0f;
            for (int t = si; t < ei; ++t) {
                int p = padidx(t);
                af += sf[p];
                am += sm[p];
            }
            float inv = 1.0f / (float)count;
            size_t o = (size_t)cbc * K + k;
            out_f[o] = af * inv;
            out_m[o] = am * inv;
        }
        __syncthreads();
    }
    #undef ROW_PARAMS
    #undef ISSUE_LOADS
}

extern "C" void kernel_launch(void* const* d_in, const int* in_sizes, int n_in,
                              void* d_out, int out_size, void* d_ws, size_t ws_size,
                              hipStream_t stream) {
    const float* f    = (const float*)d_in[0];
    const float* m    = (const float*)d_in[1];
    const int*   vlen = (const int*)d_in[2];

    // K derived from output size: out = 2 * BN * C * K floats
    int K = out_size / (2 * BN * CCH);
    if (K < 1) K = 1;

    float* out_f = (float*)d_out;
    float* out_m = out_f + (size_t)BN * CCH * K;

    int grid = (BN * CCH) / RPB;   // 2048
    pool_pipe<<<grid, 256, 0, stream>>>(f, m, vlen, out_f, out_m, K);
}